// Round 8
// baseline (280.094 us; speedup 1.0000x reference)
//
#include <hip/hip_runtime.h>

// NRI MLP decoder, single step. B=8, N=32, T=256, D=4, E=992, K=2, H=64, M=64, NH=128.
// Edge e: receiver i=e/31, jj=e%31, sender j = jj<i ? jj : jj+1.
// h1 = relu(S[j]+R[i]), S = x@W1[k][0:4]+b1 (senders first), R = x@W1[k][4:8].
// msg = relu(h1@W2[k]+b2[k]); agg[i] += msg*g[e,k]
// aug=[agg|x|0pad] -> relu(@[Wo1_agg;Wo1_x]+bo1) -> relu(@Wo2+bo2) -> @Wo3+bo3; out=x+pred.
// GEMMs via v_mfma_f32_16x16x32_f16. G=4 time-steps per block; weight fragments
// hoisted to registers once per block (amortize scattered global loads 4x).
// MFMA layout (16x16x32): A: row=l&15, k=8*(l>>4)+e; B: col=l&15, k=8*(l>>4)+e;
//                         D: col=l&15, row=4*(l>>4)+reg.

typedef _Float16 f16x8 __attribute__((ext_vector_type(8)));
typedef __fp16   f16x2 __attribute__((ext_vector_type(2)));   // cvt_pkrtz return type
typedef float    f32x4 __attribute__((ext_vector_type(4)));

union ABfrag { f16x8 v; f16x2 h[4]; };

__global__ __launch_bounds__(256, 2)
void nri_fused(const float* __restrict__ inputs,
               const float* __restrict__ rgraph,
               const float* __restrict__ W1,  const float* __restrict__ b1,
               const float* __restrict__ W2,  const float* __restrict__ b2,
               const float* __restrict__ Wo1, const float* __restrict__ bo1,
               const float* __restrict__ Wo2, const float* __restrict__ bo2,
               const float* __restrict__ Wo3, const float* __restrict__ bo3,
               float* __restrict__ out)
{
    // floats: x 0(128) | g 128(1984) | S 2112(32x68) | R 4288(32x68) |
    //         aug 6464(32x100) | h_l 9664(32x136 halves = 2176 fl) | wo3 11840(516)
    // p2 overlays S/R: 2112(32x132=4224 <= 4352).  Total 12356 fl = 49.4KB.
    __shared__ float smem[12356];
    float* x_l = smem;
    float* g_l = smem + 128;
    float* S   = smem + 2112;
    float* R   = smem + 4288;
    float* aug = smem + 6464;
    _Float16* h_l = reinterpret_cast<_Float16*>(smem + 9664);
    float* wo3_l = smem + 11840;    // 512 Wo3 + 4 bo3
    float* p2  = smem + 2112;

    const int tid  = threadIdx.x;
    const int b    = blockIdx.x >> 6;
    const int tg   = blockIdx.x & 63;       // 4 consecutive t per block
    const int w    = tid >> 6;
    const int lane = tid & 63;
    const int q    = lane & 15;
    const int g4   = lane >> 4;
    const int c0   = 32 * w;                // wave's 32-col slice of NH=128

    // ---- one-time LDS staging: g, Wo3/bo3, aug zero pad (cols 68..95) ----
    for (int idx = tid; idx < 1984; idx += 256) g_l[idx] = rgraph[idx];
    for (int idx = tid; idx < 512;  idx += 256) wo3_l[idx] = Wo3[idx];
    if (tid < 4) wo3_l[512 + tid] = bo3[tid];
    for (int idx = tid; idx < 896; idx += 256) {
        const int n = idx >> 5, c = idx & 31;
        if (c < 28) aug[n * 100 + 68 + c] = 0.f;
    }

    // ---- one-time weight fragments (registers, reused for all 4 t) ----
    ABfrag w2f[2][4][2];
    float bb[2][4];
    #pragma unroll
    for (int k = 0; k < 2; ++k)
        #pragma unroll
        for (int n = 0; n < 4; ++n) {
            bb[k][n] = b2[k * 64 + 16 * n + q];
            #pragma unroll
            for (int s = 0; s < 2; ++s)
                #pragma unroll
                for (int e2 = 0; e2 < 4; ++e2) {
                    const int ka = 32 * s + 8 * g4 + 2 * e2;
                    w2f[k][n][s].h[e2] = __builtin_amdgcn_cvt_pkrtz(
                        W2[k * 4096 + ka * 64 + 16 * n + q],
                        W2[k * 4096 + (ka + 1) * 64 + 16 * n + q]);
                }
        }
    ABfrag bf1[2][3];
    float bo1f[2];
    #pragma unroll
    for (int n = 0; n < 2; ++n) {
        const int col = c0 + 16 * n + q;
        bo1f[n] = bo1[col];
        #pragma unroll
        for (int s = 0; s < 3; ++s)
            #pragma unroll
            for (int e2 = 0; e2 < 4; ++e2) {
                const int ka = 32 * s + 8 * g4 + 2 * e2;
                const int kb = ka + 1;
                const float v0 = (ka < 64) ? Wo1[(4 + ka) * 128 + col]
                               : ((ka < 68) ? Wo1[(ka - 64) * 128 + col] : 0.f);
                const float v1 = (kb < 64) ? Wo1[(4 + kb) * 128 + col]
                               : ((kb < 68) ? Wo1[(kb - 64) * 128 + col] : 0.f);
                bf1[n][s].h[e2] = __builtin_amdgcn_cvt_pkrtz(v0, v1);
            }
    }
    ABfrag bf2[2][4];
    float bo2f[2];
    #pragma unroll
    for (int n = 0; n < 2; ++n) {
        const int col = c0 + 16 * n + q;
        bo2f[n] = bo2[col];
        #pragma unroll
        for (int s = 0; s < 4; ++s)
            #pragma unroll
            for (int e2 = 0; e2 < 4; ++e2) {
                const int ka = 32 * s + 8 * g4 + 2 * e2;
                bf2[n][s].h[e2] = __builtin_amdgcn_cvt_pkrtz(
                    Wo2[ka * 128 + col], Wo2[(ka + 1) * 128 + col]);
            }
    }

    for (int it = 0; it < 4; ++it) {
        const int t = tg * 4 + it;
        __syncthreads();                       // prior consumers of x_l/p2/aug done
        if (tid < 32)
            reinterpret_cast<float4*>(x_l)[tid] =
                *reinterpret_cast<const float4*>(
                    inputs + ((size_t)(b * 32 + tid) * 256 + t) * 4);
        __syncthreads();
        if (tid < 128) {                       // aug x-columns from LDS
            const int n = tid >> 2, c = tid & 3;
            aug[n * 100 + 64 + c] = x_l[n * 4 + c];
        }

        float agg_acc[8];
        #pragma unroll
        for (int rr = 0; rr < 8; ++rr) agg_acc[rr] = 0.f;

        for (int k = 0; k < 2; ++k) {
            if (k == 1) __syncthreads();       // edge reads of k=0 S/R done
            // ---- stage S (sender proj + b1), R (receiver proj), stride 68 ----
            for (int idx = tid; idx < 2048; idx += 256) {
                const int j = idx >> 6, kk = idx & 63;
                const float4 xj = reinterpret_cast<const float4*>(x_l)[j];
                const float* wp = W1 + k * 512 + kk;
                float s = b1[k * 64 + kk], r = 0.f;
                s = fmaf(xj.x, wp[0],   s);  r = fmaf(xj.x, wp[256], r);
                s = fmaf(xj.y, wp[64],  s);  r = fmaf(xj.y, wp[320], r);
                s = fmaf(xj.z, wp[128], s);  r = fmaf(xj.z, wp[384], r);
                s = fmaf(xj.w, wp[192], s);  r = fmaf(xj.w, wp[448], r);
                S[j * 68 + kk] = s;
                R[j * 68 + kk] = r;
            }
            __syncthreads();                   // S,R visible

            // ---- per-receiver edge GEMM, no barriers ----
            #pragma unroll
            for (int rr = 0; rr < 8; ++rr) {
                const int i = w * 8 + rr;
                float4 Rv[2][2];
                #pragma unroll
                for (int s = 0; s < 2; ++s) {
                    const float* rp = R + i * 68 + 32 * s + 8 * g4;
                    Rv[s][0] = *reinterpret_cast<const float4*>(rp);
                    Rv[s][1] = *reinterpret_cast<const float4*>(rp + 4);
                }
                ABfrag af[2][2];
                #pragma unroll
                for (int m = 0; m < 2; ++m) {
                    const int r = 16 * m + q;
                    const int j = (r == 31) ? 0 : ((r < i) ? r : r + 1);
                    #pragma unroll
                    for (int s = 0; s < 2; ++s) {
                        const float* sp = S + j * 68 + 32 * s + 8 * g4;
                        const float4 s0 = *reinterpret_cast<const float4*>(sp);
                        const float4 s1 = *reinterpret_cast<const float4*>(sp + 4);
                        af[m][s].h[0] = __builtin_amdgcn_cvt_pkrtz(
                            fmaxf(s0.x + Rv[s][0].x, 0.f), fmaxf(s0.y + Rv[s][0].y, 0.f));
                        af[m][s].h[1] = __builtin_amdgcn_cvt_pkrtz(
                            fmaxf(s0.z + Rv[s][0].z, 0.f), fmaxf(s0.w + Rv[s][0].w, 0.f));
                        af[m][s].h[2] = __builtin_amdgcn_cvt_pkrtz(
                            fmaxf(s1.x + Rv[s][1].x, 0.f), fmaxf(s1.y + Rv[s][1].y, 0.f));
                        af[m][s].h[3] = __builtin_amdgcn_cvt_pkrtz(
                            fmaxf(s1.z + Rv[s][1].z, 0.f), fmaxf(s1.w + Rv[s][1].w, 0.f));
                    }
                }
                f32x4 acc[2][4];
                #pragma unroll
                for (int m = 0; m < 2; ++m)
                    #pragma unroll
                    for (int n = 0; n < 4; ++n) {
                        acc[m][n][0] = bb[k][n]; acc[m][n][1] = bb[k][n];
                        acc[m][n][2] = bb[k][n]; acc[m][n][3] = bb[k][n];
                    }
                #pragma unroll
                for (int s = 0; s < 2; ++s)
                    #pragma unroll
                    for (int m = 0; m < 2; ++m)
                        #pragma unroll
                        for (int n = 0; n < 4; ++n)
                            acc[m][n] = __builtin_amdgcn_mfma_f32_16x16x32_f16(
                                af[m][s].v, w2f[k][n][s].v, acc[m][n], 0, 0, 0);
                float part[4] = {0.f, 0.f, 0.f, 0.f};
                #pragma unroll
                for (int m = 0; m < 2; ++m)
                    #pragma unroll
                    for (int reg = 0; reg < 4; ++reg) {
                        const int row = 16 * m + 4 * g4 + reg;
                        const float gv = (row < 31) ? g_l[(31 * i + row) * 2 + k] : 0.f;
                        #pragma unroll
                        for (int n = 0; n < 4; ++n)
                            part[n] = fmaf(fmaxf(acc[m][n][reg], 0.f), gv, part[n]);
                    }
                #pragma unroll
                for (int n = 0; n < 4; ++n) {
                    part[n] += __shfl_xor(part[n], 16);
                    part[n] += __shfl_xor(part[n], 32);
                }
                const float v = (g4 == 0) ? part[0] : (g4 == 1) ? part[1]
                              : (g4 == 2) ? part[2] : part[3];
                agg_acc[rr] += v;
            }
        }

        // ---- agg -> aug cols 0..63 ----
        #pragma unroll
        for (int rr = 0; rr < 8; ++rr)
            aug[(w * 8 + rr) * 100 + 16 * g4 + q] = agg_acc[rr];
        __syncthreads();

        // ---- node layer 1: aug(32x96) @ bf1 -> h (fp16, stride 136) ----
        {
            f32x4 acc[2][2];
            #pragma unroll
            for (int m = 0; m < 2; ++m)
                #pragma unroll
                for (int n = 0; n < 2; ++n) {
                    acc[m][n][0] = bo1f[n]; acc[m][n][1] = bo1f[n];
                    acc[m][n][2] = bo1f[n]; acc[m][n][3] = bo1f[n];
                }
            #pragma unroll
            for (int s = 0; s < 3; ++s) {
                ABfrag afr[2];
                #pragma unroll
                for (int m = 0; m < 2; ++m) {
                    const float* ap = aug + (16 * m + q) * 100 + 32 * s + 8 * g4;
                    const float4 a0 = *reinterpret_cast<const float4*>(ap);
                    const float4 a1 = *reinterpret_cast<const float4*>(ap + 4);
                    afr[m].h[0] = __builtin_amdgcn_cvt_pkrtz(a0.x, a0.y);
                    afr[m].h[1] = __builtin_amdgcn_cvt_pkrtz(a0.z, a0.w);
                    afr[m].h[2] = __builtin_amdgcn_cvt_pkrtz(a1.x, a1.y);
                    afr[m].h[3] = __builtin_amdgcn_cvt_pkrtz(a1.z, a1.w);
                }
                #pragma unroll
                for (int m = 0; m < 2; ++m)
                    #pragma unroll
                    for (int n = 0; n < 2; ++n)
                        acc[m][n] = __builtin_amdgcn_mfma_f32_16x16x32_f16(
                            afr[m].v, bf1[n][s].v, acc[m][n], 0, 0, 0);
            }
            #pragma unroll
            for (int m = 0; m < 2; ++m)
                #pragma unroll
                for (int n = 0; n < 2; ++n)
                    #pragma unroll
                    for (int reg = 0; reg < 4; ++reg) {
                        const int row = 16 * m + 4 * g4 + reg;
                        h_l[row * 136 + c0 + 16 * n + q] =
                            (_Float16)fmaxf(acc[m][n][reg], 0.f);
                    }
        }
        __syncthreads();

        // ---- node layer 2: h(32x128 fp16) @ bf2 -> p2 (fp32, stride 132) ----
        {
            f32x4 acc[2][2];
            #pragma unroll
            for (int m = 0; m < 2; ++m)
                #pragma unroll
                for (int n = 0; n < 2; ++n) {
                    acc[m][n][0] = bo2f[n]; acc[m][n][1] = bo2f[n];
                    acc[m][n][2] = bo2f[n]; acc[m][n][3] = bo2f[n];
                }
            #pragma unroll
            for (int s = 0; s < 4; ++s) {
                f16x8 afr[2];
                #pragma unroll
                for (int m = 0; m < 2; ++m)
                    afr[m] = *reinterpret_cast<const f16x8*>(
                        h_l + (16 * m + q) * 136 + 32 * s + 8 * g4);
                #pragma unroll
                for (int m = 0; m < 2; ++m)
                    #pragma unroll
                    for (int n = 0; n < 2; ++n)
                        acc[m][n] = __builtin_amdgcn_mfma_f32_16x16x32_f16(
                            afr[m], bf2[n][s].v, acc[m][n], 0, 0, 0);
            }
            #pragma unroll
            for (int m = 0; m < 2; ++m)
                #pragma unroll
                for (int n = 0; n < 2; ++n)
                    #pragma unroll
                    for (int reg = 0; reg < 4; ++reg) {
                        const int row = 16 * m + 4 * g4 + reg;
                        p2[row * 132 + c0 + 16 * n + q] = fmaxf(acc[m][n][reg], 0.f);
                    }
        }
        __syncthreads();

        // ---- layer 3 (fp32 VALU, Wo3 from LDS) + residual + store ----
        if (tid < 128 && t < 255) {
            const int rr3 = tid >> 2;
            const int dd  = tid & 3;
            float a0 = 0.f, a1 = 0.f, a2 = 0.f, a3 = 0.f;
            const float* pr = p2 + rr3 * 132;
            for (int d = 0; d < 128; d += 4) {
                a0 = fmaf(pr[d + 0], wo3_l[(d + 0) * 4 + dd], a0);
                a1 = fmaf(pr[d + 1], wo3_l[(d + 1) * 4 + dd], a1);
                a2 = fmaf(pr[d + 2], wo3_l[(d + 2) * 4 + dd], a2);
                a3 = fmaf(pr[d + 3], wo3_l[(d + 3) * 4 + dd], a3);
            }
            const float pred = ((a0 + a1) + (a2 + a3)) + wo3_l[512 + dd];
            out[((size_t)(b * 32 + rr3) * 255 + t) * 4 + dd] = x_l[rr3 * 4 + dd] + pred;
        }
    }
}

__global__ void copy_relgraph(const float* __restrict__ g, float* __restrict__ out2)
{
    const int idx = blockIdx.x * 256 + threadIdx.x;
    if (idx < 15872) out2[idx] = g[idx % 1984];
}

extern "C" void kernel_launch(void* const* d_in, const int* in_sizes, int n_in,
                              void* d_out, int out_size, void* d_ws, size_t ws_size,
                              hipStream_t stream)
{
    (void)in_sizes; (void)n_in; (void)d_ws; (void)ws_size; (void)out_size;
    const float* inputs    = (const float*)d_in[0];
    const float* rel_graph = (const float*)d_in[3];
    const float* W1  = (const float*)d_in[4];
    const float* b1  = (const float*)d_in[5];
    const float* W2  = (const float*)d_in[6];
    const float* b2  = (const float*)d_in[7];
    const float* Wo1 = (const float*)d_in[8];
    const float* bo1 = (const float*)d_in[9];
    const float* Wo2 = (const float*)d_in[10];
    const float* bo2 = (const float*)d_in[11];
    const float* Wo3 = (const float*)d_in[12];
    const float* bo3 = (const float*)d_in[13];
    float* out = (float*)d_out;

    nri_fused<<<512, 256, 0, stream>>>(inputs, rel_graph, W1, b1, W2, b2,
                                       Wo1, bo1, Wo2, bo2, Wo3, bo3, out);
    copy_relgraph<<<62, 256, 0, stream>>>(rel_graph, out + 261120);
}